// Round 9
// baseline (2390.977 us; speedup 1.0000x reference)
//
#include <hip/hip_runtime.h>

// CGLSTMEncoder via MFMA: 294912 seqs, T=120, H=32, D_IN=1.
// 16 seqs/wave, 8 mfma_f32_16x16x32_bf16 tiles/step (hi/lo bf16 split, 3
// MFMAs/tile => ~fp32). Transcendental-minimal elementwise (7 trans/elem).
// Round-14 change: MAKE 3 WAVES/SIMD FEASIBLE (regs + LDS), revert 2-batch.
//   Evidence: r6/r7/r8 reorders all land on VALUBusy=75, Mfma=28 -- the
//   75% is 2 waves x ~37.5% single-wave VALU issue (trans-chain latency
//   gaps inside each wave). Only a 3rd resident wave fills the gaps;
//   intra-wave scheduling cannot. 3 waves blocked by (a) natural regs
//   ~176 > 170 (r3) and budget-170 squeezing into spill (r2: 84/84 split,
//   WRITE_SIZE 192MB), (b) 2-batch LDS 56.8K capping 2 WGs/CU.
//   Fix: 1 batch/wave again; move wx[8]/bb[8] (16 kernel-long regs) into
//   a per-WG LDS table wb[16][20] (bank-clean, 16B rows; 4x ds_read_b128
//   per step on the idle DS pipe). Natural usage ~160 <= 170 => the
//   (256,3) budget fits WITHOUT allocator squeeze => no spill.
//   LDS/WG = 29.7K => 3 WGs/CU. Sentinel: WRITE_SIZE must stay 36864 KB.
//   Predicted: occupancy 22->33%, VALUBusy 75->90, dur -> ~1100us.
// Gate order i,f,g,o: o is dead code in the reference and skipped.
// Layouts (verified): A: m=lane&15,k=quad*8+j; B: n=lane&15 holds W rows;
// C/D: col=lane&15, row=quad*4+reg.

#define NV 9
#define TLEN 120
#define HS 32
#define BATCH_ 32768
#define NSEQ (BATCH_ * NV)
#define NBATCH (NSEQ / 16)   // 18432 batches of 16 seqs
#define WPB 4                // waves per block (independent batches)
#define GRID_ (NBATCH / WPB) // 4608 blocks, 1 batch per wave

#define TCHUNK 60            // timesteps staged per LDS refill (2 chunks)
#define XSTRIDE 20           // words per t-row of xT (16B-aligned quad reads)
#define HSTRIDE 36           // words per seq-row of hbuf
#define WBSTRIDE 20          // words per col-row of wb (16B-aligned, 2-way max)

#define LOG2E 1.4426950408889634f
#define TWOL  2.8853900817779268f

typedef __attribute__((ext_vector_type(8))) short bf16x8;
typedef __attribute__((ext_vector_type(4))) float f32x4;
typedef __attribute__((ext_vector_type(4))) unsigned int u32x4;

__device__ __forceinline__ float fast_exp2(float x) { return __builtin_amdgcn_exp2f(x); }
__device__ __forceinline__ float fast_rcp(float x)  { return __builtin_amdgcn_rcpf(x); }
__device__ __forceinline__ unsigned int fbits(float x) { return __builtin_bit_cast(unsigned int, x); }
__device__ __forceinline__ float bcastf(unsigned int x) { return __builtin_bit_cast(float, x); }

__device__ __forceinline__ f32x4 splat4(float x) { f32x4 v = {x, x, x, x}; return v; }
__device__ __forceinline__ f32x4 fma4(f32x4 a, f32x4 b, f32x4 c) {
  return __builtin_elementwise_fma(a, b, c);
}
__device__ __forceinline__ f32x4 exp24(f32x4 v) {
  f32x4 r;
  r[0] = fast_exp2(v[0]); r[1] = fast_exp2(v[1]);
  r[2] = fast_exp2(v[2]); r[3] = fast_exp2(v[3]);
  return r;
}
__device__ __forceinline__ f32x4 rcp4(f32x4 v) {
  f32x4 r;
  r[0] = fast_rcp(v[0]); r[1] = fast_rcp(v[1]);
  r[2] = fast_rcp(v[2]); r[3] = fast_rcp(v[3]);
  return r;
}

// merged-LSTM elementwise for 4 seqs: inputs are PRESCALED pre-activations
// (ai,af,ac by -log2e; ag by -2log2e); ct is the scaled cell state.
__device__ __forceinline__ void lstm_elem(f32x4 ai, f32x4 af, f32x4 ag, f32x4 ac,
                                          f32x4& ct, f32x4& h) {
  const f32x4 one4 = splat4(1.0f);
  f32x4 Ei = exp24(ai), Ef = exp24(af), Eg = exp24(ag), Ea = exp24(ac);
  f32x4 pi_ = Ei + one4, pf_ = Ef + one4, pg_ = Eg + one4, pa_ = Ea + one4;
  f32x4 u   = fma4(Eg, splat4(TWOL), splat4(-TWOL));   // (-2L)*(1-Eg)
  f32x4 P   = pi_ * pg_;
  f32x4 tt  = pf_ * u;
  f32x4 num = fma4(ct, P, tt);
  f32x4 den = pf_ * P;
  ct = num * rcp4(den);
  f32x4 Ec  = exp24(ct);
  h = (one4 - Ec) * rcp4(pa_ * (Ec + one4));
}

__global__ __launch_bounds__(256, 3) void cglstm_kernel(
    const float* __restrict__ x,      // [B, NV*TLEN]
    const float* __restrict__ W_ih,   // [128, 1]
    const float* __restrict__ W_hh,   // [128, 32]
    const float* __restrict__ b_ih,   // [128]
    const float* __restrict__ b_hh,   // [128]
    const float* __restrict__ cg_w,   // [32, 1]
    const float* __restrict__ cg_u,   // [32, 32]
    const float* __restrict__ cg_b,   // [32]
    float* __restrict__ out)          // flat [s*HS + j]
{
  const int lane = threadIdx.x & 63;
  const int wid  = threadIdx.x >> 6;
  const int col  = lane & 15;
  const int quad = lane >> 4;

  // per-wave LDS slices; wb is WG-shared (identical values, each wave
  // writes it redundantly before reading -> wave-internal ordering only)
  __shared__ __align__(16) float xT[WPB][TCHUNK * XSTRIDE];
  __shared__ __align__(16) unsigned int hbuf[WPB][16 * HSTRIDE];
  __shared__ __align__(16) float wb[16][WBSTRIDE];  // [col]: wx[0..7], bb[0..7]
  float* __restrict__ xTw = xT[wid];
  unsigned int* hb = hbuf[wid];

  // ---- one-time: prescaled B fragments (W rows) as bf16 hi/lo ----
  bf16x8 bhi[8], blo[8];
#pragma unroll
  for (int tile = 0; tile < 8; ++tile) {
    const int n = col + (tile & 1) * 16;
    const float sc_ = ((tile >> 1) == 2) ? -TWOL : -LOG2E;  // g gate: -2L
    const float* wrow = (tile < 6) ? (W_hh + (size_t)((tile >> 1) * HS + n) * HS)
                                   : (cg_u + (size_t)n * HS);
    bf16x8 vh, vl;
#pragma unroll
    for (int e = 0; e < 8; ++e) {
      float wv = wrow[quad * 8 + e] * sc_;
      unsigned int wbits = fbits(wv);
      float lo_f = wv - bcastf(wbits & 0xffff0000u);
      vh[e] = (short)(wbits >> 16);
      vl[e] = (short)(fbits(lo_f) >> 16);
    }
    bhi[tile] = vh; blo[tile] = vl;
    // wx/bb go to LDS (live-range shrink: 16 kernel-long regs -> table)
    float wxv, bbv;
    if (tile < 6) {
      const int gg = tile >> 1;
      wxv = W_ih[gg * HS + n] * sc_;
      bbv = (b_ih[gg * HS + n] + b_hh[gg * HS + n]) * sc_;
    } else {
      wxv = cg_w[n] * sc_;
      bbv = cg_b[n] * sc_;
    }
    if (quad == 0) {
      wb[col][tile]     = wxv;
      wb[col][8 + tile] = bbv;
    }
  }

  const int p = blockIdx.x * WPB + wid;      // one 16-seq batch per wave
  const float4* xb = (const float4*)(x + (size_t)p * 16 * TLEN);

  for (int i = lane; i < 16 * HSTRIDE; i += 64) hb[i] = 0u;
  f32x4 ct0 = splat4(0.f), ct1 = splat4(0.f), h0 = splat4(0.f), h1 = splat4(0.f);

#pragma unroll 1
  for (int chunk = 0; chunk < 2; ++chunk) {
    // ---- stage x^T for 60 timesteps (16 seqs: 960 floats = 240 float4) ----
    // each seq row is 30 float4; chunk offset = 15 float4
    for (int i = lane; i < 240; i += 64) {
      int s = i / 15;
      int j = i - s * 15;
      float4 v = xb[s * 30 + chunk * 15 + j];
      int t0 = j * 4;
      xTw[(t0 + 0) * XSTRIDE + s] = v.x;
      xTw[(t0 + 1) * XSTRIDE + s] = v.y;
      xTw[(t0 + 2) * XSTRIDE + s] = v.z;
      xTw[(t0 + 3) * XSTRIDE + s] = v.w;
    }
    // wave-internal LDS ordering: DS pipe is in-order per wave, no barrier

#pragma unroll 1
    for (int tl = 0; tl < TCHUNK; ++tl) {
      // x for this lane's 4 seqs: one 16B broadcast read
      f32x4 xt4 = *(const f32x4*)&xTw[tl * XSTRIDE + quad * 4];
      // wx/bb from LDS (broadcast across quads; 2-way max bank aliasing)
      f32x4 wx03 = *(const f32x4*)&wb[col][0];
      f32x4 wx47 = *(const f32x4*)&wb[col][4];
      f32x4 bb03 = *(const f32x4*)&wb[col][8];
      f32x4 bb47 = *(const f32x4*)&wb[col][12];
      f32x4 acc[8];
#pragma unroll
      for (int t = 0; t < 4; ++t)
        acc[t] = fma4(splat4(wx03[t]), xt4, splat4(bb03[t]));
#pragma unroll
      for (int t = 0; t < 4; ++t)
        acc[4 + t] = fma4(splat4(wx47[t]), xt4, splat4(bb47[t]));
      // A fragments: h[m=col][k=quad*8..+7], hi/lo from packed words
      const unsigned int* hrow = &hb[col * HSTRIDE + quad * 8];
      u32x4 wa = *(const u32x4*)hrow;
      u32x4 wz = *(const u32x4*)(hrow + 4);
      u32x4 hi4, lo4;
      hi4[0] = __builtin_amdgcn_perm(wa[1], wa[0], 0x05040100u);
      hi4[1] = __builtin_amdgcn_perm(wa[3], wa[2], 0x05040100u);
      hi4[2] = __builtin_amdgcn_perm(wz[1], wz[0], 0x05040100u);
      hi4[3] = __builtin_amdgcn_perm(wz[3], wz[2], 0x05040100u);
      lo4[0] = __builtin_amdgcn_perm(wa[1], wa[0], 0x07060302u);
      lo4[1] = __builtin_amdgcn_perm(wa[3], wa[2], 0x07060302u);
      lo4[2] = __builtin_amdgcn_perm(wz[1], wz[0], 0x07060302u);
      lo4[3] = __builtin_amdgcn_perm(wz[3], wz[2], 0x07060302u);
      bf16x8 ahi = __builtin_bit_cast(bf16x8, hi4);
      bf16x8 alo = __builtin_bit_cast(bf16x8, lo4);
      // 3 passes of 8 independent MFMAs (r7 order; bit-identical per acc)
#pragma unroll
      for (int tile = 0; tile < 8; ++tile)
        acc[tile] = __builtin_amdgcn_mfma_f32_16x16x32_bf16(ahi, bhi[tile], acc[tile], 0, 0, 0);
#pragma unroll
      for (int tile = 0; tile < 8; ++tile)
        acc[tile] = __builtin_amdgcn_mfma_f32_16x16x32_bf16(alo, bhi[tile], acc[tile], 0, 0, 0);
#pragma unroll
      for (int tile = 0; tile < 8; ++tile)
        acc[tile] = __builtin_amdgcn_mfma_f32_16x16x32_bf16(ahi, blo[tile], acc[tile], 0, 0, 0);
      // merged elementwise (7 trans/element), halves j=col and j=col+16
      lstm_elem(acc[0], acc[2], acc[4], acc[6], ct0, h0);
      lstm_elem(acc[1], acc[3], acc[5], acc[7], ct1, h1);
      // pack h -> (bf16hi | bf16lo) words for next step's A fragments
#pragma unroll
      for (int r = 0; r < 4; ++r) {
        unsigned int hbits = fbits(h0[r]);
        float lof = h0[r] - bcastf(hbits & 0xffff0000u);
        hb[(quad * 4 + r) * HSTRIDE + col] =
            __builtin_amdgcn_perm(fbits(lof), hbits, 0x07060302u);
        unsigned int hbits1 = fbits(h1[r]);
        float lof1 = h1[r] - bcastf(hbits1 & 0xffff0000u);
        hb[(quad * 4 + r) * HSTRIDE + col + 16] =
            __builtin_amdgcn_perm(fbits(lof1), hbits1, 0x07060302u);
      }
      // no barrier: same-wave DS ordering guarantees h(t) visible at t+1
    }
  }

  // ---- epilogue ----
  float* ob = out + (size_t)p * 16 * HS;
#pragma unroll
  for (int r = 0; r < 4; ++r) {
    ob[(quad * 4 + r) * HS + col]      = h0[r];
    ob[(quad * 4 + r) * HS + col + 16] = h1[r];
  }
}

extern "C" void kernel_launch(void* const* d_in, const int* in_sizes, int n_in,
                              void* d_out, int out_size, void* d_ws, size_t ws_size,
                              hipStream_t stream) {
  const float* x    = (const float*)d_in[0];
  const float* W_ih = (const float*)d_in[1];
  const float* W_hh = (const float*)d_in[2];
  const float* b_ih = (const float*)d_in[3];
  const float* b_hh = (const float*)d_in[4];
  const float* cg_w = (const float*)d_in[5];
  const float* cg_u = (const float*)d_in[6];
  const float* cg_b = (const float*)d_in[7];
  float* out = (float*)d_out;

  dim3 grid(GRID_), block(256);
  hipLaunchKernelGGL(cglstm_kernel, grid, block, 0, stream,
                     x, W_ih, W_hh, b_ih, b_hh, cg_w, cg_u, cg_b, out);
}

// Round 10
// 1366.508 us; speedup vs baseline: 1.7497x; 1.7497x over previous
//
#include <hip/hip_runtime.h>

// CGLSTMEncoder via MFMA: 294912 seqs, T=120, H=32, D_IN=1.
// 16 seqs/wave, 8 mfma_f32_16x16x32_bf16 tiles/step (hi/lo bf16 split, 3
// MFMAs/tile => ~fp32). Transcendental-minimal elementwise (7 trans/elem).
// Round-15 change: 3 WAVES/SIMD VIA DEMAND REDUCTION, NOT BUDGET FORCING.
//   Evidence: (256,3) spills identically in r2 and r9 -- the allocator
//   rigidly splits 84 arch / 86 agpr under a 170 budget and spills the
//   rest (r9: VGPR=84, WRITE_SIZE 230MB). But r9 ALSO proved occupancy
//   reaches 34% when LDS allows. And r3 showed natural demand = 176 --
//   only 6 regs over the 3-wave line. Fix: keep (256,2) (never spills)
//   and CUT 32 regs of demand: blo[8] B-fragments move to a WG-shared
//   LDS table, re-read per tile in the K-step. HW occupancy follows
//   actual allocation (~144 total -> 3 waves/SIMD), not launch_bounds.
//   * ALL LDS in one pooled array: pack-stores may alias the table, so
//     LICM cannot hoist the loop-invariant blo reads back into registers.
//   * All 4 waves write identical table values -> wave-internal ordering,
//     still ZERO barriers.
//   * Issue-port model (6 reorder nulls): VALUBusy+MfmaUtil pinned at
//     ~103% -- port serializes; only a 3rd wave fills the 25% idle.
//   Sentinels: WRITE_SIZE must stay 36864 KB; occupancy must leave ~22%.
// Gate order i,f,g,o: o is dead code in the reference and skipped.
// Layouts (verified): A: m=lane&15,k=quad*8+j; B: n=lane&15 holds W rows;
// C/D: col=lane&15, row=quad*4+reg.

#define NV 9
#define TLEN 120
#define HS 32
#define BATCH_ 32768
#define NSEQ (BATCH_ * NV)
#define NBATCH (NSEQ / 16)   // 18432 batches of 16 seqs
#define WPB 4                // waves per block (independent batches)
#define GRID_ (NBATCH / WPB) // 4608 blocks, 1 batch per wave

#define TCHUNK 60            // timesteps staged per LDS refill (2 chunks)
#define XSTRIDE 20           // words per t-row of xT (16B-aligned quad reads)
#define HSTRIDE 36           // words per seq-row of hbuf

// pooled LDS layout (u32 words)
#define XT_WORDS   (TCHUNK * XSTRIDE)        // 1200 per wave
#define HB_WORDS   (16 * HSTRIDE)            // 576 per wave
#define XT_OFF     0                         // 4 * 1200 = 4800
#define HB_OFF     (WPB * XT_WORDS)          // 4800
#define BLO_OFF    (HB_OFF + WPB * HB_WORDS) // 7104; blo: 8*64*4 = 2048
#define POOL_WORDS (BLO_OFF + 8 * 64 * 4)    // 9152 words = 36608 B

#define LOG2E 1.4426950408889634f
#define TWOL  2.8853900817779268f

typedef __attribute__((ext_vector_type(8))) short bf16x8;
typedef __attribute__((ext_vector_type(4))) float f32x4;
typedef __attribute__((ext_vector_type(4))) unsigned int u32x4;

__device__ __forceinline__ float fast_exp2(float x) { return __builtin_amdgcn_exp2f(x); }
__device__ __forceinline__ float fast_rcp(float x)  { return __builtin_amdgcn_rcpf(x); }
__device__ __forceinline__ unsigned int fbits(float x) { return __builtin_bit_cast(unsigned int, x); }
__device__ __forceinline__ float bcastf(unsigned int x) { return __builtin_bit_cast(float, x); }

__device__ __forceinline__ f32x4 splat4(float x) { f32x4 v = {x, x, x, x}; return v; }
__device__ __forceinline__ f32x4 fma4(f32x4 a, f32x4 b, f32x4 c) {
  return __builtin_elementwise_fma(a, b, c);
}
__device__ __forceinline__ f32x4 exp24(f32x4 v) {
  f32x4 r;
  r[0] = fast_exp2(v[0]); r[1] = fast_exp2(v[1]);
  r[2] = fast_exp2(v[2]); r[3] = fast_exp2(v[3]);
  return r;
}
__device__ __forceinline__ f32x4 rcp4(f32x4 v) {
  f32x4 r;
  r[0] = fast_rcp(v[0]); r[1] = fast_rcp(v[1]);
  r[2] = fast_rcp(v[2]); r[3] = fast_rcp(v[3]);
  return r;
}

// merged-LSTM elementwise for 4 seqs: inputs are PRESCALED pre-activations
// (ai,af,ac by -log2e; ag by -2log2e); ct is the scaled cell state.
__device__ __forceinline__ void lstm_elem(f32x4 ai, f32x4 af, f32x4 ag, f32x4 ac,
                                          f32x4& ct, f32x4& h) {
  const f32x4 one4 = splat4(1.0f);
  f32x4 Ei = exp24(ai), Ef = exp24(af), Eg = exp24(ag), Ea = exp24(ac);
  f32x4 pi_ = Ei + one4, pf_ = Ef + one4, pg_ = Eg + one4, pa_ = Ea + one4;
  f32x4 u   = fma4(Eg, splat4(TWOL), splat4(-TWOL));   // (-2L)*(1-Eg)
  f32x4 P   = pi_ * pg_;
  f32x4 tt  = pf_ * u;
  f32x4 num = fma4(ct, P, tt);
  f32x4 den = pf_ * P;
  ct = num * rcp4(den);
  f32x4 Ec  = exp24(ct);
  h = (one4 - Ec) * rcp4(pa_ * (Ec + one4));
}

__global__ __launch_bounds__(256, 2) void cglstm_kernel(
    const float* __restrict__ x,      // [B, NV*TLEN]
    const float* __restrict__ W_ih,   // [128, 1]
    const float* __restrict__ W_hh,   // [128, 32]
    const float* __restrict__ b_ih,   // [128]
    const float* __restrict__ b_hh,   // [128]
    const float* __restrict__ cg_w,   // [32, 1]
    const float* __restrict__ cg_u,   // [32, 32]
    const float* __restrict__ cg_b,   // [32]
    float* __restrict__ out)          // flat [s*HS + j]
{
  const int lane = threadIdx.x & 63;
  const int wid  = threadIdx.x >> 6;
  const int col  = lane & 15;
  const int quad = lane >> 4;

  // ONE pooled LDS object: xT | hbuf | blo table. Pack-stores may alias
  // the blo reads, so the compiler keeps the (loop-invariant) blo loads
  // inside the loop instead of hoisting them into 32 registers.
  __shared__ __align__(16) unsigned int pool[POOL_WORDS];
  float* __restrict__ xTw = (float*)&pool[XT_OFF + wid * XT_WORDS];
  unsigned int* hb = &pool[HB_OFF + wid * HB_WORDS];
  u32x4* blo_t = (u32x4*)&pool[BLO_OFF];       // [tile*64 + lane]

  // ---- one-time: prescaled B fragments (W rows) as bf16 hi/lo ----
  // bhi stays in registers (32); blo goes to the shared LDS table.
  bf16x8 bhi[8];
  float wx[8], bb[8];
#pragma unroll
  for (int tile = 0; tile < 8; ++tile) {
    const int n = col + (tile & 1) * 16;
    const float sc_ = ((tile >> 1) == 2) ? -TWOL : -LOG2E;  // g gate: -2L
    const float* wrow = (tile < 6) ? (W_hh + (size_t)((tile >> 1) * HS + n) * HS)
                                   : (cg_u + (size_t)n * HS);
    bf16x8 vh, vl;
#pragma unroll
    for (int e = 0; e < 8; ++e) {
      float wv = wrow[quad * 8 + e] * sc_;
      unsigned int wbits = fbits(wv);
      float lo_f = wv - bcastf(wbits & 0xffff0000u);
      vh[e] = (short)(wbits >> 16);
      vl[e] = (short)(fbits(lo_f) >> 16);
    }
    bhi[tile] = vh;
    // every wave writes identical values -> wave-internal ordering only
    blo_t[tile * 64 + lane] = __builtin_bit_cast(u32x4, vl);
    if (tile < 6) {
      const int gg = tile >> 1;
      wx[tile] = W_ih[gg * HS + n] * sc_;
      bb[tile] = (b_ih[gg * HS + n] + b_hh[gg * HS + n]) * sc_;
    } else {
      wx[tile] = cg_w[n] * sc_;
      bb[tile] = cg_b[n] * sc_;
    }
  }

  const int p = blockIdx.x * WPB + wid;      // one 16-seq batch per wave
  const float4* xb = (const float4*)(x + (size_t)p * 16 * TLEN);

  for (int i = lane; i < 16 * HSTRIDE; i += 64) hb[i] = 0u;
  f32x4 ct0 = splat4(0.f), ct1 = splat4(0.f), h0 = splat4(0.f), h1 = splat4(0.f);

#pragma unroll 1
  for (int chunk = 0; chunk < 2; ++chunk) {
    // ---- stage x^T for 60 timesteps (16 seqs: 960 floats = 240 float4) ----
    // each seq row is 30 float4; chunk offset = 15 float4
    for (int i = lane; i < 240; i += 64) {
      int s = i / 15;
      int j = i - s * 15;
      float4 v = xb[s * 30 + chunk * 15 + j];
      int t0 = j * 4;
      xTw[(t0 + 0) * XSTRIDE + s] = v.x;
      xTw[(t0 + 1) * XSTRIDE + s] = v.y;
      xTw[(t0 + 2) * XSTRIDE + s] = v.z;
      xTw[(t0 + 3) * XSTRIDE + s] = v.w;
    }
    // wave-internal LDS ordering: DS pipe is in-order per wave, no barrier

#pragma unroll 1
    for (int tl = 0; tl < TCHUNK; ++tl) {
      // x for this lane's 4 seqs: one 16B broadcast read
      f32x4 xt4 = *(const f32x4*)&xTw[tl * XSTRIDE + quad * 4];
      f32x4 acc[8];
#pragma unroll
      for (int tile = 0; tile < 8; ++tile)
        acc[tile] = fma4(splat4(wx[tile]), xt4, splat4(bb[tile]));
      // A fragments: h[m=col][k=quad*8..+7], hi/lo from packed words
      const unsigned int* hrow = &hb[col * HSTRIDE + quad * 8];
      u32x4 wa = *(const u32x4*)hrow;
      u32x4 wz = *(const u32x4*)(hrow + 4);
      u32x4 hi4, lo4;
      hi4[0] = __builtin_amdgcn_perm(wa[1], wa[0], 0x05040100u);
      hi4[1] = __builtin_amdgcn_perm(wa[3], wa[2], 0x05040100u);
      hi4[2] = __builtin_amdgcn_perm(wz[1], wz[0], 0x05040100u);
      hi4[3] = __builtin_amdgcn_perm(wz[3], wz[2], 0x05040100u);
      lo4[0] = __builtin_amdgcn_perm(wa[1], wa[0], 0x07060302u);
      lo4[1] = __builtin_amdgcn_perm(wa[3], wa[2], 0x07060302u);
      lo4[2] = __builtin_amdgcn_perm(wz[1], wz[0], 0x07060302u);
      lo4[3] = __builtin_amdgcn_perm(wz[3], wz[2], 0x07060302u);
      bf16x8 ahi = __builtin_bit_cast(bf16x8, hi4);
      bf16x8 alo = __builtin_bit_cast(bf16x8, lo4);
      // per-tile: hh, lh chained; hl uses blo re-read from LDS (short
      // live range ~3 tiles; scheduler hoists loads within the phase)
#pragma unroll
      for (int tile = 0; tile < 8; ++tile) {
        bf16x8 blo_c = __builtin_bit_cast(bf16x8, blo_t[tile * 64 + lane]);
        acc[tile] = __builtin_amdgcn_mfma_f32_16x16x32_bf16(ahi, bhi[tile], acc[tile], 0, 0, 0);
        acc[tile] = __builtin_amdgcn_mfma_f32_16x16x32_bf16(alo, bhi[tile], acc[tile], 0, 0, 0);
        acc[tile] = __builtin_amdgcn_mfma_f32_16x16x32_bf16(ahi, blo_c, acc[tile], 0, 0, 0);
      }
      // merged elementwise (7 trans/element), halves j=col and j=col+16
      lstm_elem(acc[0], acc[2], acc[4], acc[6], ct0, h0);
      lstm_elem(acc[1], acc[3], acc[5], acc[7], ct1, h1);
      // pack h -> (bf16hi | bf16lo) words for next step's A fragments
#pragma unroll
      for (int r = 0; r < 4; ++r) {
        unsigned int hbits = fbits(h0[r]);
        float lof = h0[r] - bcastf(hbits & 0xffff0000u);
        hb[(quad * 4 + r) * HSTRIDE + col] =
            __builtin_amdgcn_perm(fbits(lof), hbits, 0x07060302u);
        unsigned int hbits1 = fbits(h1[r]);
        float lof1 = h1[r] - bcastf(hbits1 & 0xffff0000u);
        hb[(quad * 4 + r) * HSTRIDE + col + 16] =
            __builtin_amdgcn_perm(fbits(lof1), hbits1, 0x07060302u);
      }
      // no barrier: same-wave DS ordering guarantees h(t) visible at t+1
    }
  }

  // ---- epilogue ----
  float* ob = out + (size_t)p * 16 * HS;
#pragma unroll
  for (int r = 0; r < 4; ++r) {
    ob[(quad * 4 + r) * HS + col]      = h0[r];
    ob[(quad * 4 + r) * HS + col + 16] = h1[r];
  }
}

extern "C" void kernel_launch(void* const* d_in, const int* in_sizes, int n_in,
                              void* d_out, int out_size, void* d_ws, size_t ws_size,
                              hipStream_t stream) {
  const float* x    = (const float*)d_in[0];
  const float* W_ih = (const float*)d_in[1];
  const float* W_hh = (const float*)d_in[2];
  const float* b_ih = (const float*)d_in[3];
  const float* b_hh = (const float*)d_in[4];
  const float* cg_w = (const float*)d_in[5];
  const float* cg_u = (const float*)d_in[6];
  const float* cg_b = (const float*)d_in[7];
  float* out = (float*)d_out;

  dim3 grid(GRID_), block(256);
  hipLaunchKernelGGL(cglstm_kernel, grid, block, 0, stream,
                     x, W_ih, W_hh, b_ih, b_hh, cg_w, cg_u, cg_b, out);
}